// Round 1
// baseline (77.384 us; speedup 1.0000x reference)
//
#include <hip/hip_runtime.h>
#include <hip/hip_bf16.h>

#define NB 4096
#define NTB 32   // 4096 / 128 row-tiles

typedef short v8s __attribute__((ext_vector_type(8)));
typedef float v4f __attribute__((ext_vector_type(4)));

// ws layout: sq[4096] f32 (16 KB) | xb[4096*128] bf16 (1 MB) | P[32][32][128] float2 (1 MB)
// P[bi][bj][r]: partial (num, den) for row r of row-block bi, contributed by the
// unique block covering ordered pair (bi, bj). No atomics; every slot written once.

__global__ __launch_bounds__(256) void prep_kernel(const float* __restrict__ x,
        float* __restrict__ sq, float* __restrict__ out,
        unsigned short* __restrict__ xb) {
    int tid = threadIdx.x;
    int row = blockIdx.x * 8 + (tid >> 5);   // 32 threads per row
    int lane = tid & 31;
    const float4* xg = (const float4*)x;
    float4 v = xg[row * 32 + lane];
    __hip_bfloat16 h0 = __float2bfloat16(v.x), h1 = __float2bfloat16(v.y);
    __hip_bfloat16 h2 = __float2bfloat16(v.z), h3 = __float2bfloat16(v.w);
    ushort4 u4;
    u4.x = *(unsigned short*)&h0; u4.y = *(unsigned short*)&h1;
    u4.z = *(unsigned short*)&h2; u4.w = *(unsigned short*)&h3;
    ((ushort4*)xb)[row * 32 + lane] = u4;
    float s = v.x * v.x + v.y * v.y + v.z * v.z + v.w * v.w;
    #pragma unroll
    for (int off = 16; off > 0; off >>= 1) s += __shfl_down(s, off);
    if (lane == 0) sq[row] = s;
    if (blockIdx.x == 0 && tid == 0) out[0] = 0.f;
}

// One block per upper-triangular 128x128 tile (528 blocks). MFMA fragments are
// loaded DIRECTLY from L2-resident xb (fragment layout row=l&15, kchunk=l>>4 is
// a coalesced 16B/lane pattern covering full 64B lines) -- no LDS tiles, no
// staging barrier. Off-diagonal tiles emit both row- and (via symmetry of e and
// the mask) column-partials.
__global__ __launch_bounds__(256) void snn_sym(const unsigned short* __restrict__ xb,
        const int* __restrict__ y, const float* __restrict__ sqg,
        float2* __restrict__ P) {
    __shared__ float part[2][128][34];     // [wn][row][lr] float2, padded 17
    __shared__ float2 part2[2][128];       // [wm][col] column partials
    __shared__ float sqi[128], sqj[128];
    __shared__ int yi[128], yj[128];

    const int tid = threadIdx.x;
    const int wave = tid >> 6;
    const int lane = tid & 63;
    const int wm = wave >> 1;      // 0..1 : 64-row half
    const int wn = wave & 1;       // 0..1 : 64-col half
    const int lr = lane & 15;
    const int q  = lane >> 4;      // 0..3

    // triangular decode: blockIdx.x -> (bi, bj), bj >= bi
    int t = blockIdx.x, bi = 0, rem = NTB;
    while (t >= rem) { t -= rem; ++bi; --rem; }
    const int bj = bi + t;
    const int i0 = bi * 128, j0 = bj * 128;

    if (tid < 128) {
        sqi[tid] = sqg[i0 + tid]; sqj[tid] = sqg[j0 + tid];
        yi[tid] = y[i0 + tid];    yj[tid] = y[j0 + tid];
    }

    const v8s* xg = (const v8s*)xb;                          // 16 chunks/row
    const v8s* arow = xg + (i0 + wm * 64 + lr) * 16 + q;     // frag base, A side
    const v8s* brow = xg + (j0 + wn * 64 + lr) * 16 + q;     // frag base, B side

    v4f acc[4][4];
    #pragma unroll
    for (int mt = 0; mt < 4; ++mt)
        #pragma unroll
        for (int nt = 0; nt < 4; ++nt)
            acc[mt][nt] = (v4f){0.f, 0.f, 0.f, 0.f};

    #pragma unroll
    for (int kk = 0; kk < 4; ++kk) {          // K = 4 x 32
        v8s af[4], bf[4];
        #pragma unroll
        for (int mt = 0; mt < 4; ++mt) af[mt] = arow[mt * 256 + kk * 4];
        #pragma unroll
        for (int nt = 0; nt < 4; ++nt) bf[nt] = brow[nt * 256 + kk * 4];
        #pragma unroll
        for (int mt = 0; mt < 4; ++mt)
            #pragma unroll
            for (int nt = 0; nt < 4; ++nt)
                acc[mt][nt] = __builtin_amdgcn_mfma_f32_16x16x32_bf16(
                    af[mt], bf[nt], acc[mt][nt], 0, 0, 0);
    }

    __syncthreads();   // sqi/sqj/yi/yj ready

    // fused epilogue: dist -> exp -> masked row AND column partials
    float sqj_r[4]; int yj_r[4], jgl[4];
    #pragma unroll
    for (int nt = 0; nt < 4; ++nt) {
        int jc = wn * 64 + nt * 16 + lr;
        sqj_r[nt] = sqj[jc]; yj_r[nt] = yj[jc]; jgl[nt] = j0 + jc;
    }
    float cn[4] = {0.f, 0.f, 0.f, 0.f}, cd[4] = {0.f, 0.f, 0.f, 0.f};
    #pragma unroll
    for (int mt = 0; mt < 4; ++mt) {
        #pragma unroll
        for (int r = 0; r < 4; ++r) {
            int rloc = wm * 64 + mt * 16 + q * 4 + r;   // C/D: row = q*4+reg
            float si = sqi[rloc]; int yir = yi[rloc]; int ig = i0 + rloc;
            float n = 0.f, d = 0.f;
            #pragma unroll
            for (int nt = 0; nt < 4; ++nt) {
                float dist = fmaxf(si + sqj_r[nt] - 2.f * acc[mt][nt][r], 0.f);
                float e = __builtin_amdgcn_exp2f(dist * -0.014426950408889634f); // exp(-dist/100)
                d += e;
                float me = (yir == yj_r[nt] && ig != jgl[nt]) ? e : 0.f;
                n += me;
                cd[nt] += e; cn[nt] += me;
            }
            *(float2*)&part[wn][rloc][lr * 2] = make_float2(n, d);
        }
    }
    // column partials: reduce over q (lane bits 4,5); valid rows = this wave's 64
    #pragma unroll
    for (int nt = 0; nt < 4; ++nt) {
        float n2 = cn[nt] + __shfl_xor(cn[nt], 16); n2 += __shfl_xor(n2, 32);
        float d2 = cd[nt] + __shfl_xor(cd[nt], 16); d2 += __shfl_xor(d2, 32);
        if (q == 0) part2[wm][wn * 64 + nt * 16 + lr] = make_float2(n2, d2);
    }
    __syncthreads();

    // row partial block-reduce + store: 2 threads per row sum 16 float2 each
    {
        int row = tid >> 1, h = tid & 1;
        const float2* p = (const float2*)&part[h][row][0];
        float sn = 0.f, sd = 0.f;
        #pragma unroll
        for (int c = 0; c < 16; ++c) { float2 v = p[c]; sn += v.x; sd += v.y; }
        sn += __shfl_down(sn, 1); sd += __shfl_down(sd, 1);
        if (h == 0) P[(bi * NTB + bj) * 128 + row] = make_float2(sn, sd);
    }
    // column contribution (transposed pairs) -- off-diagonal blocks only
    if (bi != bj && tid < 128) {
        float2 a = part2[0][tid], b = part2[1][tid];
        P[(bj * NTB + bi) * 128 + tid] = make_float2(a.x + b.x, a.y + b.y);
    }
}

__global__ __launch_bounds__(256) void snn_final(const float2* __restrict__ P,
        float* __restrict__ out) {
    __shared__ float wsum[4];
    int i = blockIdx.x * 256 + threadIdx.x;
    int ib = i >> 7, il = i & 127;
    float n = 0.f, d = 0.f;
    #pragma unroll
    for (int s = 0; s < NTB; ++s) {
        float2 v = P[(ib * NTB + s) * 128 + il];
        n += v.x; d += v.y;
    }
    float l = -__logf(n / d);
    #pragma unroll
    for (int off = 32; off > 0; off >>= 1) l += __shfl_down(l, off);
    if ((threadIdx.x & 63) == 0) wsum[threadIdx.x >> 6] = l;
    __syncthreads();
    if (threadIdx.x == 0)
        atomicAdd(out, (wsum[0] + wsum[1] + wsum[2] + wsum[3]) * (1.0f / NB));
}

extern "C" void kernel_launch(void* const* d_in, const int* in_sizes, int n_in,
                              void* d_out, int out_size, void* d_ws, size_t ws_size,
                              hipStream_t stream) {
    const float* x = (const float*)d_in[0];
    const int*   y = (const int*)d_in[1];
    float* out = (float*)d_out;
    float* sq  = (float*)d_ws;
    unsigned short* xb = (unsigned short*)(sq + NB);
    float2* P = (float2*)(xb + NB * 128);

    prep_kernel<<<NB / 8, 256, 0, stream>>>(x, sq, out, xb);
    snn_sym<<<NTB * (NTB + 1) / 2, 256, 0, stream>>>(xb, y, sq, P);
    snn_final<<<NB / 256, 256, 0, stream>>>(P, out);
}

// Round 2
// 74.538 us; speedup vs baseline: 1.0382x; 1.0382x over previous
//
#include <hip/hip_runtime.h>
#include <hip/hip_bf16.h>

#define NB 4096
#define NTB 32   // 4096 / 128 row-tiles

typedef short v8s __attribute__((ext_vector_type(8)));
typedef float v4f __attribute__((ext_vector_type(4)));

// ws layout: sq[4096] f32 (16 KB) | xb[4096*128] bf16 (1 MB) | P[32][32][128] float2 (1 MB)
// P[bi][bj][r]: partial (num, den) for row r of row-block bi, contributed by the
// unique block covering ordered pair (bi, bj). No atomics; every slot written once.

__global__ __launch_bounds__(256) void prep_kernel(const float* __restrict__ x,
        float* __restrict__ sq, float* __restrict__ out,
        unsigned short* __restrict__ xb) {
    int tid = threadIdx.x;
    int row = blockIdx.x * 8 + (tid >> 5);   // 32 threads per row
    int lane = tid & 31;
    const float4* xg = (const float4*)x;
    float4 v = xg[row * 32 + lane];
    __hip_bfloat16 h0 = __float2bfloat16(v.x), h1 = __float2bfloat16(v.y);
    __hip_bfloat16 h2 = __float2bfloat16(v.z), h3 = __float2bfloat16(v.w);
    ushort4 u4;
    u4.x = *(unsigned short*)&h0; u4.y = *(unsigned short*)&h1;
    u4.z = *(unsigned short*)&h2; u4.w = *(unsigned short*)&h3;
    ((ushort4*)xb)[row * 32 + lane] = u4;
    float s = v.x * v.x + v.y * v.y + v.z * v.z + v.w * v.w;
    #pragma unroll
    for (int off = 16; off > 0; off >>= 1) s += __shfl_down(s, off);
    if (lane == 0) sq[row] = s;
    if (blockIdx.x == 0 && tid == 0) out[0] = 0.f;
}

// One block per upper-triangular 128x128 tile (528 blocks). Round-0's proven
// LDS-staged MFMA pipeline (padded-136 tiles, conflict-free ds_read_b128
// fragments); triangular symmetry: off-diagonal tiles emit both row partials
// (rows of bi) and column partials (rows of bj) from the same exp() values.
__global__ __launch_bounds__(256) void snn_sym(const unsigned short* __restrict__ xb,
        const int* __restrict__ y, const float* __restrict__ sqg,
        float2* __restrict__ P) {
    __shared__ __align__(16) union {
        unsigned short tiles[2 * 128 * 136];   // 69632 B
        float part[2 * 128 * 34];              // 34816 B  [wn][row][17 float2]
    } sm;
    __shared__ float2 part2[2][128];           // [wm][col] column partials
    __shared__ float sqi[128], sqj[128];
    __shared__ int yi[128], yj[128];

    const int tid = threadIdx.x;
    const int wave = tid >> 6;
    const int lane = tid & 63;
    const int wm = wave >> 1;      // 0..1 : 64-row half
    const int wn = wave & 1;       // 0..1 : 64-col half
    const int lr = lane & 15;
    const int q  = lane >> 4;      // 0..3

    // triangular decode: blockIdx.x -> (bi, bj), bj >= bi
    int t = blockIdx.x, bi = 0, rem = NTB;
    while (t >= rem) { t -= rem; ++bi; --rem; }
    const int bj = bi + t;
    const int i0 = bi * 128, j0 = bj * 128;
    const bool diag = (bi == bj);

    const v8s* xg = (const v8s*)xb;   // 16 chunks of 8 bf16 per row
    unsigned short* At = sm.tiles;
    unsigned short* Bt = diag ? sm.tiles : sm.tiles + 128 * 136;

    // stage A (and B when off-diagonal) tiles: coalesced 16B chunks
    #pragma unroll
    for (int r = 0; r < 8; ++r) {
        int c = r * 256 + tid;
        int row = c >> 4, cc = c & 15;
        *(v8s*)&At[row * 136 + cc * 8] = xg[(i0 + row) * 16 + cc];
        if (!diag)
            *(v8s*)&Bt[row * 136 + cc * 8] = xg[(j0 + row) * 16 + cc];
    }
    if (tid < 128) {
        sqi[tid] = sqg[i0 + tid]; sqj[tid] = sqg[j0 + tid];
        yi[tid] = y[i0 + tid];    yj[tid] = y[j0 + tid];
    }
    __syncthreads();

    v4f acc[4][4];
    #pragma unroll
    for (int mt = 0; mt < 4; ++mt)
        #pragma unroll
        for (int nt = 0; nt < 4; ++nt)
            acc[mt][nt] = (v4f){0.f, 0.f, 0.f, 0.f};

    #pragma unroll
    for (int kk = 0; kk < 4; ++kk) {          // K = 4 x 32
        v8s af[4], bf[4];
        #pragma unroll
        for (int mt = 0; mt < 4; ++mt)
            af[mt] = *(const v8s*)&At[(wm * 64 + mt * 16 + lr) * 136 + kk * 32 + q * 8];
        #pragma unroll
        for (int nt = 0; nt < 4; ++nt)
            bf[nt] = *(const v8s*)&Bt[(wn * 64 + nt * 16 + lr) * 136 + kk * 32 + q * 8];
        #pragma unroll
        for (int mt = 0; mt < 4; ++mt)
            #pragma unroll
            for (int nt = 0; nt < 4; ++nt)
                acc[mt][nt] = __builtin_amdgcn_mfma_f32_16x16x32_bf16(
                    af[mt], bf[nt], acc[mt][nt], 0, 0, 0);
    }

    __syncthreads();   // all waves done reading tiles before part[] overwrites

    // fused epilogue: dist -> exp -> masked row AND column partials
    float sqj_r[4]; int yj_r[4], jgl[4];
    #pragma unroll
    for (int nt = 0; nt < 4; ++nt) {
        int jc = wn * 64 + nt * 16 + lr;
        sqj_r[nt] = sqj[jc]; yj_r[nt] = yj[jc]; jgl[nt] = j0 + jc;
    }
    float cn[4] = {0.f, 0.f, 0.f, 0.f}, cd[4] = {0.f, 0.f, 0.f, 0.f};
    #pragma unroll
    for (int mt = 0; mt < 4; ++mt) {
        #pragma unroll
        for (int r = 0; r < 4; ++r) {
            int rloc = wm * 64 + mt * 16 + q * 4 + r;   // C/D: row = q*4+reg
            float si = sqi[rloc]; int yir = yi[rloc]; int ig = i0 + rloc;
            float n = 0.f, d = 0.f;
            #pragma unroll
            for (int nt = 0; nt < 4; ++nt) {
                float dist = fmaxf(si + sqj_r[nt] - 2.f * acc[mt][nt][r], 0.f);
                float e = __builtin_amdgcn_exp2f(dist * -0.014426950408889634f); // exp(-dist/100)
                d += e;
                float me = (yir == yj_r[nt] && ig != jgl[nt]) ? e : 0.f;
                n += me;
                cd[nt] += e; cn[nt] += me;
            }
            *(float2*)&sm.part[((wn * 128 + rloc) * 17 + lr) * 2] = make_float2(n, d);
        }
    }
    // column partials: reduce over q (lane bits 4,5)
    #pragma unroll
    for (int nt = 0; nt < 4; ++nt) {
        float n2 = cn[nt] + __shfl_xor(cn[nt], 16); n2 += __shfl_xor(n2, 32);
        float d2 = cd[nt] + __shfl_xor(cd[nt], 16); d2 += __shfl_xor(d2, 32);
        if (q == 0) part2[wm][wn * 64 + nt * 16 + lr] = make_float2(n2, d2);
    }
    __syncthreads();

    // row partial block-reduce + store: 2 threads per row sum 16 float2 each
    {
        int row = tid >> 1, h = tid & 1;
        const float2* p = (const float2*)&sm.part[(h * 128 + row) * 34];
        float sn = 0.f, sd = 0.f;
        #pragma unroll
        for (int c = 0; c < 16; ++c) { float2 v = p[c]; sn += v.x; sd += v.y; }
        sn += __shfl_down(sn, 1); sd += __shfl_down(sd, 1);
        if (h == 0) P[(bi * NTB + bj) * 128 + row] = make_float2(sn, sd);
    }
    // column contribution (transposed pairs) -- off-diagonal blocks only
    if (!diag && tid < 128) {
        float2 a = part2[0][tid], b = part2[1][tid];
        P[(bj * NTB + bi) * 128 + tid] = make_float2(a.x + b.x, a.y + b.y);
    }
}

__global__ __launch_bounds__(256) void snn_final(const float2* __restrict__ P,
        float* __restrict__ out) {
    __shared__ float wsum[4];
    int i = blockIdx.x * 256 + threadIdx.x;
    int ib = i >> 7, il = i & 127;
    float n = 0.f, d = 0.f;
    #pragma unroll
    for (int s = 0; s < NTB; ++s) {
        float2 v = P[(ib * NTB + s) * 128 + il];
        n += v.x; d += v.y;
    }
    float l = -__logf(n / d);
    #pragma unroll
    for (int off = 32; off > 0; off >>= 1) l += __shfl_down(l, off);
    if ((threadIdx.x & 63) == 0) wsum[threadIdx.x >> 6] = l;
    __syncthreads();
    if (threadIdx.x == 0)
        atomicAdd(out, (wsum[0] + wsum[1] + wsum[2] + wsum[3]) * (1.0f / NB));
}

extern "C" void kernel_launch(void* const* d_in, const int* in_sizes, int n_in,
                              void* d_out, int out_size, void* d_ws, size_t ws_size,
                              hipStream_t stream) {
    const float* x = (const float*)d_in[0];
    const int*   y = (const int*)d_in[1];
    float* out = (float*)d_out;
    float* sq  = (float*)d_ws;
    unsigned short* xb = (unsigned short*)(sq + NB);
    float2* P = (float2*)(xb + NB * 128);

    prep_kernel<<<NB / 8, 256, 0, stream>>>(x, sq, out, xb);
    snn_sym<<<NTB * (NTB + 1) / 2, 256, 0, stream>>>(xb, y, sq, P);
    snn_final<<<NB / 256, 256, 0, stream>>>(P, out);
}